// Round 8
// baseline (119.318 us; speedup 1.0000x reference)
//
#include <hip/hip_runtime.h>

// Moreau-tropical forward, round 8: register-tiled two-pass, VMEM-fed (no LDS
// tiles), high occupancy.
//
// z = x[b] + W[n] (D=1024); root of f(tau)=sum relu(z-tau)=lam in [M-lam, M],
// M = max(z); only z > M-lam contribute. Block = 8b x 8n = 64 pairs, 256 thr;
// wave = quadrant (tb,tn in 2x2), lane = d-group (16 d's: k*256 + lane*4).
// Pass 1: coalesced 1KB wave-loads straight from L2 (no staging, no barriers),
// 4x4 register tile of running maxes. Wave shfl-reduce (16 indep chains) ->
// pmax. Pass 2: per-(thread,pair) EXACT gate m[q] > thr (thread holds a
// candidate iff true), reload 16B pieces L1/L2-hot, rare atomic inserts.
// Solve: one wave, thread-per-pair register bisection (proven r4-r7, absmax 0).
// LDS = 12.5 KB (cand+pmax+pcnt only) -> occupancy VGPR-bound, 16 waves/CU.

#define D_DIM   1024
#define TB      8
#define TN      8
#define NPAIR   64
#define NTHR    256
#define CAPP    32
#define NB      16
#define NEG_INF (-3.0e38f)

__global__ void __launch_bounds__(NTHR, 4)
moreau_tropical(const float* __restrict__ x, const float* __restrict__ W,
                const float* __restrict__ lam_p, float* __restrict__ out,
                int B, int N) {
    __shared__ float cand[CAPP * NPAIR];   // cand[slot*64 + p]: conflict-free
    __shared__ float pmax[NPAIR];
    __shared__ int   pcnt[NPAIR];

    const int tid  = threadIdx.x;
    const int lane = tid & 63;
    const int wq   = tid >> 6;           // wave id -> 2x2 quadrant
    const int tb   = wq >> 1;
    const int tn   = wq & 1;
    const int b0   = blockIdx.y * TB;
    const int n0   = blockIdx.x * TN;
    const float lam = lam_p[0];

    if (tid < NPAIR) pcnt[tid] = 0;

    // row pointers (lane offset folded in); wave-loads are 64 x 16B = 1KB coalesced
    const float* xr[4];
    const float* wr[4];
#pragma unroll
    for (int i = 0; i < 4; ++i)
        xr[i] = x + (size_t)min(b0 + tb * 4 + i, B - 1) * D_DIM + lane * 4;
#pragma unroll
    for (int j = 0; j < 4; ++j)
        wr[j] = W + (size_t)min(n0 + tn * 4 + j, N - 1) * D_DIM + lane * 4;

    // ---- pass 1: 4x4 running maxes over this lane's 16 d's ----
    float m[16];
#pragma unroll
    for (int q = 0; q < 16; ++q) m[q] = NEG_INF;

#pragma unroll
    for (int k = 0; k < 4; ++k) {
        float4 xv[4], wv[4];
#pragma unroll
        for (int i = 0; i < 4; ++i) xv[i] = *(const float4*)(xr[i] + k * 256);
#pragma unroll
        for (int j = 0; j < 4; ++j) wv[j] = *(const float4*)(wr[j] + k * 256);
#pragma unroll
        for (int i = 0; i < 4; ++i)
#pragma unroll
            for (int j = 0; j < 4; ++j) {
                const float4 a = xv[i], c = wv[j];
                const float z0 = a.x + c.x, z1 = a.y + c.y;
                const float z2 = a.z + c.z, z3 = a.w + c.w;
                m[i * 4 + j] = fmaxf(m[i * 4 + j],
                                     fmaxf(fmaxf(z0, z1), fmaxf(z2, z3)));
            }
    }

    // ---- full-wave max per pair: 16 independent shfl chains; lane 0 publishes ----
#pragma unroll
    for (int q = 0; q < 16; ++q) {
        float v = m[q];
#pragma unroll
        for (int o = 1; o < 64; o <<= 1) v = fmaxf(v, __shfl_xor(v, o, 64));
        if (lane == 0)
            pmax[(tb * 4 + (q >> 2)) * 8 + tn * 4 + (q & 3)] = v;
    }
    __syncthreads();

    // ---- pass 2: exact per-(thread,pair) gate, rare inserts ----
#pragma unroll
    for (int q = 0; q < 16; ++q) {
        const int i = q >> 2, j = q & 3;
        const int p = (tb * 4 + i) * 8 + tn * 4 + j;
        const float thr = pmax[p] - lam;
        if (m[q] > thr) {        // this lane's 16 d's hold >=1 candidate for p
#pragma unroll
            for (int k = 0; k < 4; ++k) {
                const float4 a = *(const float4*)(xr[i] + k * 256);
                const float4 c = *(const float4*)(wr[j] + k * 256);
                const float z0 = a.x + c.x, z1 = a.y + c.y;
                const float z2 = a.z + c.z, z3 = a.w + c.w;
                if (z0 > thr) { int s_ = atomicAdd(&pcnt[p], 1); if (s_ < CAPP) cand[s_ * NPAIR + p] = z0; }
                if (z1 > thr) { int s_ = atomicAdd(&pcnt[p], 1); if (s_ < CAPP) cand[s_ * NPAIR + p] = z1; }
                if (z2 > thr) { int s_ = atomicAdd(&pcnt[p], 1); if (s_ < CAPP) cand[s_ * NPAIR + p] = z2; }
                if (z3 > thr) { int s_ = atomicAdd(&pcnt[p], 1); if (s_ < CAPP) cand[s_ * NPAIR + p] = z3; }
            }
        }
    }
    __syncthreads();

    // ---- solve: one wave, thread-per-pair (proven rounds 4-7) ----
    if (tid < NPAIR) {
        const int p  = tid;
        const int pb = p >> 3;
        const int pn = p & 7;
        const int K  = pcnt[p];
        const float M    = pmax[p];
        const float thr0 = M - lam;
        float tau, delta;

        if (K <= CAPP) {
            int Kw = K;
#pragma unroll
            for (int o = 1; o < 64; o <<= 1) Kw = max(Kw, __shfl_xor(Kw, o, 64));

            float lo = thr0, hi = M;
            for (int it = 0; it < NB; ++it) {
                const float mid = 0.5f * (lo + hi);
                float f = 0.0f;
                for (int j = 0; j < Kw; ++j) {
                    float v = cand[j * NPAIR + p];
                    v = (j < K) ? v : NEG_INF;
                    f += fmaxf(v - mid, 0.0f);
                }
                if (f > lam) lo = mid; else hi = mid;
            }
            tau = 0.5f * (lo + hi);
            float s2 = 0.0f;
            for (int j = 0; j < Kw; ++j) {
                float v = cand[j * NPAIR + p];
                v = (j < K) ? v : NEG_INF;
                const float t = fmaxf(v - tau, 0.0f);
                s2 += t * t;
            }
            delta = s2 / (2.0f * lam);
        } else {
            // overflow fallback (~never): stream rows from global (L2-hot)
            const float* xrow = x + (size_t)min(b0 + pb, B - 1) * D_DIM;
            const float* wrow = W + (size_t)min(n0 + pn, N - 1) * D_DIM;
            float lo = thr0, hi = M;
            for (int it = 0; it < NB; ++it) {
                const float mid = 0.5f * (lo + hi);
                float f = 0.0f;
                for (int d = 0; d < D_DIM; ++d)
                    f += fmaxf(xrow[d] + wrow[d] - mid, 0.0f);
                if (f > lam) lo = mid; else hi = mid;
            }
            tau = 0.5f * (lo + hi);
            float s2 = 0.0f;
            for (int d = 0; d < D_DIM; ++d) {
                const float t = fmaxf(xrow[d] + wrow[d] - tau, 0.0f);
                s2 += t * t;
            }
            delta = s2 / (2.0f * lam);
        }

        const int ob = min(b0 + pb, B - 1);
        const int on = min(n0 + pn, N - 1);
        out[(size_t)ob * N + on] = tau + delta;
    }
}

extern "C" void kernel_launch(void* const* d_in, const int* in_sizes, int n_in,
                              void* d_out, int out_size, void* d_ws, size_t ws_size,
                              hipStream_t stream) {
    const float* x    = (const float*)d_in[0];
    const float* W    = (const float*)d_in[1];
    const float* lamp = (const float*)d_in[2];
    float* out        = (float*)d_out;

    const int B = in_sizes[0] / D_DIM;
    const int N = in_sizes[1] / D_DIM;

    dim3 grid((N + TN - 1) / TN, (B + TB - 1) / TB);
    moreau_tropical<<<grid, NTHR, 0, stream>>>(x, W, lamp, out, B, N);
}

// Round 9
// 115.603 us; speedup vs baseline: 1.0321x; 1.0321x over previous
//
#include <hip/hip_runtime.h>

// Moreau-tropical forward, round 9: D-chunked LDS tiles (4 blocks/CU) +
// register-gated sparse pass 2.
//
// z = x[b] + W[n] (D=1024); root of f(tau)=sum relu(z-tau)=lam in [M-lam, M],
// M = max(z); only z > M-lam contribute. Block = 8b x 8n = 64 pairs, 256 thr;
// wave = 2x2 quadrant (4b x 4n pair tile), lane = d-slice. D split into two
// 512-float chunks staged in 32 KB of LDS (total LDS 39.4 KB -> 4 blocks/CU,
// 16 waves/CU -- 2x round 7). Pass 1 keeps per-thread per-chunk slice maxes
// (mA/mB); full max via 16 independent 6-step shfl chains. Pass 2 rescans a
// (thread,pair,chunk) cell ONLY if its slice max beats thr (~0.4 gates/thread
// total) -- chunk1 is still LDS-resident at that point (no restage); chunk0 is
// restaged once. Solve: one wave, thread-per-pair register bisection (proven
// rounds 4-8, absmax 0.0).

#define D_DIM   1024
#define CHUNK   512
#define TB      8
#define TN      8
#define NPAIR   64
#define NTHR    256
#define CAPP    24            // P(K>24) ~ 1e-11/pair; overflow fallback retained
#define NB      16
#define NEG_INF (-3.0e38f)

__global__ void __launch_bounds__(NTHR, 4)
moreau_tropical(const float* __restrict__ x, const float* __restrict__ W,
                const float* __restrict__ lam_p, float* __restrict__ out,
                int B, int N) {
    __shared__ float xs[TB * CHUNK];        // 16 KB (stride 512: b128 reads = free 2-way alias)
    __shared__ float ws[TN * CHUNK];        // 16 KB
    __shared__ float cand[CAPP * NPAIR];    // 6 KB, cand[slot*64 + p]
    __shared__ float pmax[NPAIR];
    __shared__ int   pcnt[NPAIR];

    const int tid  = threadIdx.x;
    const int lane = tid & 63;
    const int wq   = tid >> 6;             // wave -> 2x2 quadrant
    const int tb   = wq >> 1;
    const int tn   = wq & 1;
    const int b0   = blockIdx.y * TB;
    const int n0   = blockIdx.x * TN;
    const float lam = lam_p[0];

    if (tid < NPAIR) pcnt[tid] = 0;

    // ---- staging helper: chunk d0 (coalesced dwordx4 -> LDS) ----
#define STAGE(d0)                                                              \
    {                                                                          \
        _Pragma("unroll")                                                      \
        for (int i = 0; i < 4; ++i) {                                          \
            const int flat = tid + NTHR * i;     /* 0..1023 */                 \
            const int row  = flat >> 7;          /* 0..7    */                 \
            const int c4   = (flat & 127) << 2;  /* 0..508  */                 \
            const int gb   = min(b0 + row, B - 1);                             \
            const int gn   = min(n0 + row, N - 1);                             \
            *(float4*)&xs[row * CHUNK + c4] =                                  \
                *(const float4*)(x + (size_t)gb * D_DIM + (d0) + c4);          \
            *(float4*)&ws[row * CHUNK + c4] =                                  \
                *(const float4*)(W + (size_t)gn * D_DIM + (d0) + c4);          \
        }                                                                      \
    }

    // ---- pass-1 sweep of the resident chunk into slice-max array MC ----
#define SWEEP(MC)                                                              \
    {                                                                          \
        _Pragma("unroll")                                                      \
        for (int k = 0; k < 2; ++k) {                                          \
            const int col = (k * 64 + lane) * 4;                               \
            float4 xv[4], wv[4];                                               \
            _Pragma("unroll")                                                  \
            for (int i = 0; i < 4; ++i)                                        \
                xv[i] = *(const float4*)&xs[(tb * 4 + i) * CHUNK + col];       \
            _Pragma("unroll")                                                  \
            for (int j = 0; j < 4; ++j)                                        \
                wv[j] = *(const float4*)&ws[(tn * 4 + j) * CHUNK + col];       \
            _Pragma("unroll")                                                  \
            for (int i = 0; i < 4; ++i)                                        \
                _Pragma("unroll")                                              \
                for (int j = 0; j < 4; ++j) {                                  \
                    const float4 a = xv[i], c = wv[j];                         \
                    const float z0 = a.x + c.x, z1 = a.y + c.y;                \
                    const float z2 = a.z + c.z, z3 = a.w + c.w;                \
                    MC[i * 4 + j] = fmaxf(MC[i * 4 + j],                       \
                        fmaxf(fmaxf(z0, z1), fmaxf(z2, z3)));                  \
                }                                                              \
        }                                                                      \
    }

    // ---- pass-2 gated rescan of the resident chunk ----
#define GATHER(MC)                                                             \
    {                                                                          \
        _Pragma("unroll")                                                      \
        for (int q = 0; q < 16; ++q) {                                         \
            if (MC[q] > thr[q]) {          /* rare: ~0.4 per thread total */   \
                const int i = q >> 2, j = q & 3;                               \
                const int p = (tb * 4 + i) * 8 + tn * 4 + j;                   \
                const float t = thr[q];                                        \
                _Pragma("unroll")                                              \
                for (int k = 0; k < 2; ++k) {                                  \
                    const int col = (k * 64 + lane) * 4;                       \
                    const float4 a = *(const float4*)&xs[(tb*4+i)*CHUNK + col];\
                    const float4 c = *(const float4*)&ws[(tn*4+j)*CHUNK + col];\
                    const float z0 = a.x + c.x, z1 = a.y + c.y;                \
                    const float z2 = a.z + c.z, z3 = a.w + c.w;                \
                    if (z0 > t) { int s_ = atomicAdd(&pcnt[p], 1); if (s_ < CAPP) cand[s_ * NPAIR + p] = z0; } \
                    if (z1 > t) { int s_ = atomicAdd(&pcnt[p], 1); if (s_ < CAPP) cand[s_ * NPAIR + p] = z1; } \
                    if (z2 > t) { int s_ = atomicAdd(&pcnt[p], 1); if (s_ < CAPP) cand[s_ * NPAIR + p] = z2; } \
                    if (z3 > t) { int s_ = atomicAdd(&pcnt[p], 1); if (s_ < CAPP) cand[s_ * NPAIR + p] = z3; } \
                }                                                              \
            }                                                                  \
        }                                                                      \
    }

    float mA[16], mB[16];
#pragma unroll
    for (int q = 0; q < 16; ++q) { mA[q] = NEG_INF; mB[q] = NEG_INF; }

    STAGE(0);
    __syncthreads();
    SWEEP(mA);
    __syncthreads();            // chunk-0 readers done before overwrite
    STAGE(CHUNK);
    __syncthreads();
    SWEEP(mB);

    // ---- full per-pair max: 16 independent shfl chains; owning wave publishes ----
#pragma unroll
    for (int q = 0; q < 16; ++q) {
        float v = fmaxf(mA[q], mB[q]);
#pragma unroll
        for (int o = 1; o < 64; o <<= 1) v = fmaxf(v, __shfl_xor(v, o, 64));
        if (lane == 0)
            pmax[(tb * 4 + (q >> 2)) * 8 + tn * 4 + (q & 3)] = v;
    }
    __syncthreads();

    float thr[16];
#pragma unroll
    for (int q = 0; q < 16; ++q)
        thr[q] = pmax[(tb * 4 + (q >> 2)) * 8 + tn * 4 + (q & 3)] - lam;

    GATHER(mB);                 // chunk 1 still resident
    __syncthreads();            // gather readers done before restage
    STAGE(0);
    __syncthreads();
    GATHER(mA);
    __syncthreads();

#undef STAGE
#undef SWEEP
#undef GATHER

    // ---- solve: one wave, thread-per-pair (proven rounds 4-8) ----
    if (tid < NPAIR) {
        const int p  = tid;
        const int pb = p >> 3;
        const int pn = p & 7;
        const int K  = pcnt[p];
        const float M    = pmax[p];
        const float thr0 = M - lam;
        float tau, delta;

        if (K <= CAPP) {
            int Kw = K;
#pragma unroll
            for (int o = 1; o < 64; o <<= 1) Kw = max(Kw, __shfl_xor(Kw, o, 64));

            float lo = thr0, hi = M;
            for (int it = 0; it < NB; ++it) {
                const float mid = 0.5f * (lo + hi);
                float f = 0.0f;
                for (int j = 0; j < Kw; ++j) {
                    float v = cand[j * NPAIR + p];
                    v = (j < K) ? v : NEG_INF;
                    f += fmaxf(v - mid, 0.0f);
                }
                if (f > lam) lo = mid; else hi = mid;
            }
            tau = 0.5f * (lo + hi);
            float s2 = 0.0f;
            for (int j = 0; j < Kw; ++j) {
                float v = cand[j * NPAIR + p];
                v = (j < K) ? v : NEG_INF;
                const float t = fmaxf(v - tau, 0.0f);
                s2 += t * t;
            }
            delta = s2 / (2.0f * lam);
        } else {
            // overflow fallback (~never): stream rows from global (L2-hot)
            const float* xrow = x + (size_t)min(b0 + pb, B - 1) * D_DIM;
            const float* wrow = W + (size_t)min(n0 + pn, N - 1) * D_DIM;
            float lo = thr0, hi = M;
            for (int it = 0; it < NB; ++it) {
                const float mid = 0.5f * (lo + hi);
                float f = 0.0f;
                for (int d = 0; d < D_DIM; ++d)
                    f += fmaxf(xrow[d] + wrow[d] - mid, 0.0f);
                if (f > lam) lo = mid; else hi = mid;
            }
            tau = 0.5f * (lo + hi);
            float s2 = 0.0f;
            for (int d = 0; d < D_DIM; ++d) {
                const float t = fmaxf(xrow[d] + wrow[d] - tau, 0.0f);
                s2 += t * t;
            }
            delta = s2 / (2.0f * lam);
        }

        const int ob = min(b0 + pb, B - 1);
        const int on = min(n0 + pn, N - 1);
        out[(size_t)ob * N + on] = tau + delta;
    }
}

extern "C" void kernel_launch(void* const* d_in, const int* in_sizes, int n_in,
                              void* d_out, int out_size, void* d_ws, size_t ws_size,
                              hipStream_t stream) {
    const float* x    = (const float*)d_in[0];
    const float* W    = (const float*)d_in[1];
    const float* lamp = (const float*)d_in[2];
    float* out        = (float*)d_out;

    const int B = in_sizes[0] / D_DIM;
    const int N = in_sizes[1] / D_DIM;

    dim3 grid((N + TN - 1) / TN, (B + TB - 1) / TB);
    moreau_tropical<<<grid, NTHR, 0, stream>>>(x, W, lamp, out, B, N);
}

// Round 10
// 107.864 us; speedup vs baseline: 1.1062x; 1.0717x over previous
//
#include <hip/hip_runtime.h>

// Moreau-tropical forward, round 10: lane-owns-pair over a transposed-W LDS
// tile. z = x[b] + W[n] (D=1024); root of f(tau)=sum relu(z-tau)=lam lies in
// [M-lam, M], M = max(z); only z > M-lam contribute.
//
// Hot loop has ZERO cross-lane ops and ZERO branches: per d, one conflict-free
// ds_read (wt[d][lane], stride-65 rows -> bank (d+n)%32) shared by 2 b-rows,
// plus 2 v_add + 2 v_max. x[b][d] is wave-uniform -> scalar s_load (free pipe).
// Per-pair max lives in ONE register per b (lane = pair): no shuffle chains;
// block merge is a tiny LDS pass. Pass 2 re-sweeps with exact thresholds in
// registers and rare exec-masked atomic inserts (machinery proven r4-r9,
// absmax 0.0). Block = 2b x 64n = 128 pairs, 512 thr (8 waves x 16-d slices
// of a 128-d chunk); grid 512 blocks = 2 blocks/CU (co-resident block hides
// barrier drains), 16 waves/CU.

#define D_DIM   1024
#define CHD     128            // d per staged chunk
#define NCHUNK  (D_DIM / CHD)  // 8
#define STR     65             // wt row stride (dwords): read/write conflict-free
#define BB      2              // b rows per block
#define NN      64             // n per block (= lanes)
#define NPAIR   (BB * NN)      // 128
#define NTHR    512
#define SLICE   (CHD / 8)      // 16 d per wave per chunk
#define CAPP    24
#define NB      16
#define NEG_INF (-3.0e38f)

__global__ void __launch_bounds__(NTHR, 4)
moreau_tropical(const float* __restrict__ x, const float* __restrict__ W,
                const float* __restrict__ lam_p, float* __restrict__ out,
                int B, int N) {
    __shared__ float wt[CHD * STR];        // 33.3 KB transposed W chunk
    __shared__ float pm[8 * NPAIR];        // 4 KB per-wave partial maxes
    __shared__ float thrs[NPAIR];
    __shared__ float pmaxs[NPAIR];
    __shared__ float cand[CAPP * NPAIR];   // 12.3 KB cand[slot*128 + p]
    __shared__ int   pcnt[NPAIR];

    const int tid  = threadIdx.x;
    const int lane = tid & 63;             // lane = n within tile
    const int wq   = tid >> 6;             // wave id -> d sub-slice
    const int n0   = blockIdx.x * NN;
    const int b0   = blockIdx.y * BB;
    const float lam = lam_p[0];

    const float* xr0 = x + (size_t)min(b0 + 0, B - 1) * D_DIM;
    const float* xr1 = x + (size_t)min(b0 + 1, B - 1) * D_DIM;

    if (tid < NPAIR) pcnt[tid] = 0;

    // ---- staging: chunk c -> wt[d][n] transposed (4xb128 global, 16 ds_write) ----
#define STAGE(c)                                                               \
    {                                                                          \
        _Pragma("unroll")                                                      \
        for (int i = 0; i < 4; ++i) {                                          \
            const int flat = tid + NTHR * i;        /* 0..2047 */              \
            const int n    = flat >> 5;             /* 0..63   */              \
            const int dd   = (flat & 31) << 2;      /* 0..124  */              \
            const float4 v = *(const float4*)(W + (size_t)min(n0 + n, N - 1)   \
                                              * D_DIM + (c) * CHD + dd);       \
            wt[(dd + 0) * STR + n] = v.x;                                      \
            wt[(dd + 1) * STR + n] = v.y;                                      \
            wt[(dd + 2) * STR + n] = v.z;                                      \
            wt[(dd + 3) * STR + n] = v.w;                                      \
        }                                                                      \
    }

    // ---- pass 1: running per-pair maxes (lane-private, branch-free) ----
    float m0 = NEG_INF, m1 = NEG_INF;
#pragma unroll 1
    for (int c = 0; c < NCHUNK; ++c) {
        __syncthreads();               // previous chunk's readers done
        STAGE(c);
        __syncthreads();
        const int dbase = c * CHD + wq * SLICE;
#pragma unroll
        for (int d = 0; d < SLICE; ++d) {
            const float wv = wt[(wq * SLICE + d) * STR + lane];
            const float xa = xr0[dbase + d];        // wave-uniform -> s_load
            const float xb = xr1[dbase + d];
            m0 = fmaxf(m0, wv + xa);
            m1 = fmaxf(m1, wv + xb);
        }
    }

    pm[wq * NPAIR + lane]      = m0;
    pm[wq * NPAIR + 64 + lane] = m1;
    __syncthreads();

    if (tid < NPAIR) {
        float M = pm[tid];
#pragma unroll
        for (int k = 1; k < 8; ++k) M = fmaxf(M, pm[k * NPAIR + tid]);
        pmaxs[tid] = M;
        thrs[tid]  = M - lam;
    }
    __syncthreads();

    const float th0 = thrs[lane];
    const float th1 = thrs[64 + lane];

    // ---- pass 2: exact-threshold extraction (rare exec-masked inserts) ----
#pragma unroll 1
    for (int c = 0; c < NCHUNK; ++c) {
        STAGE(c);
        __syncthreads();
        const int dbase = c * CHD + wq * SLICE;
#pragma unroll
        for (int d = 0; d < SLICE; ++d) {
            const float wv = wt[(wq * SLICE + d) * STR + lane];
            const float z0 = wv + xr0[dbase + d];
            const float z1 = wv + xr1[dbase + d];
            if (z0 > th0) { int s_ = atomicAdd(&pcnt[lane], 1);      if (s_ < CAPP) cand[s_ * NPAIR + lane]      = z0; }
            if (z1 > th1) { int s_ = atomicAdd(&pcnt[64 + lane], 1); if (s_ < CAPP) cand[s_ * NPAIR + 64 + lane] = z1; }
        }
        __syncthreads();               // gather done before restage
    }
#undef STAGE

    // ---- solve: 2 waves, thread-per-pair (proven rounds 4-9) ----
    if (tid < NPAIR) {
        const int p  = tid;
        const int pb = p >> 6;
        const int pn = p & 63;
        const int K  = pcnt[p];
        const float M    = pmaxs[p];
        const float thr0 = M - lam;
        float tau, delta;

        if (K <= CAPP) {
            int Kw = K;
#pragma unroll
            for (int o = 1; o < 64; o <<= 1) Kw = max(Kw, __shfl_xor(Kw, o, 64));

            float lo = thr0, hi = M;
            for (int it = 0; it < NB; ++it) {
                const float mid = 0.5f * (lo + hi);
                float f = 0.0f;
                for (int j = 0; j < Kw; ++j) {
                    float v = cand[j * NPAIR + p];
                    v = (j < K) ? v : NEG_INF;
                    f += fmaxf(v - mid, 0.0f);
                }
                if (f > lam) lo = mid; else hi = mid;
            }
            tau = 0.5f * (lo + hi);
            float s2 = 0.0f;
            for (int j = 0; j < Kw; ++j) {
                float v = cand[j * NPAIR + p];
                v = (j < K) ? v : NEG_INF;
                const float t = fmaxf(v - tau, 0.0f);
                s2 += t * t;
            }
            delta = s2 / (2.0f * lam);
        } else {
            // overflow fallback (~never): stream rows from global (L2-hot)
            const float* xrow = x + (size_t)min(b0 + pb, B - 1) * D_DIM;
            const float* wrow = W + (size_t)min(n0 + pn, N - 1) * D_DIM;
            float lo = thr0, hi = M;
            for (int it = 0; it < NB; ++it) {
                const float mid = 0.5f * (lo + hi);
                float f = 0.0f;
                for (int d = 0; d < D_DIM; ++d)
                    f += fmaxf(xrow[d] + wrow[d] - mid, 0.0f);
                if (f > lam) lo = mid; else hi = mid;
            }
            tau = 0.5f * (lo + hi);
            float s2 = 0.0f;
            for (int d = 0; d < D_DIM; ++d) {
                const float t = fmaxf(xrow[d] + wrow[d] - tau, 0.0f);
                s2 += t * t;
            }
            delta = s2 / (2.0f * lam);
        }

        const int ob = min(b0 + pb, B - 1);
        const int on = min(n0 + pn, N - 1);
        out[(size_t)ob * N + on] = tau + delta;
    }
}

extern "C" void kernel_launch(void* const* d_in, const int* in_sizes, int n_in,
                              void* d_out, int out_size, void* d_ws, size_t ws_size,
                              hipStream_t stream) {
    const float* x    = (const float*)d_in[0];
    const float* W    = (const float*)d_in[1];
    const float* lamp = (const float*)d_in[2];
    float* out        = (float*)d_out;

    const int B = in_sizes[0] / D_DIM;
    const int N = in_sizes[1] / D_DIM;

    dim3 grid((N + NN - 1) / NN, (B + BB - 1) / BB);
    moreau_tropical<<<grid, NTHR, 0, stream>>>(x, W, lamp, out, B, N);
}